// Round 15
// baseline (462.092 us; speedup 1.0000x reference)
//
#include <hip/hip_runtime.h>
#include <math.h>

#define B_ 2
#define S_ 1024
#define HID 4096
#define NH 32
#define NKV 8
#define HD 128
#define LOG2E 1.44269504088896340736f

typedef short s16x8 __attribute__((ext_vector_type(8)));
typedef float f32x4 __attribute__((ext_vector_type(4)));
typedef int i32x4 __attribute__((ext_vector_type(4)));
typedef unsigned short u16;
typedef unsigned uint4v __attribute__((ext_vector_type(4)));
typedef signed char s8;

__device__ __forceinline__ i32x4 mfma_i8(i32x4 a, i32x4 b, i32x4 c) {
  return __builtin_amdgcn_mfma_i32_16x16x64_i8(a, b, c, 0, 0, 0);
}
__device__ __forceinline__ float get_scale(const unsigned* sc, int slot) {
  return fmaxf(__uint_as_float(sc[slot]) / 127.0f, 1e-8f);
}
__device__ __forceinline__ int q127(float x, float s) {
  return (int)fminf(fmaxf(rintf(x / s), -127.f), 127.f);
}
__device__ __forceinline__ unsigned pack4(float4 v, float s) {
  return (q127(v.x, s) & 255) | ((q127(v.y, s) & 255) << 8) |
         ((q127(v.z, s) & 255) << 16) | ((q127(v.w, s) & 255) << 24);
}
__device__ __forceinline__ float max4(float4 v) {
  return fmaxf(fmaxf(fabsf(v.x), fabsf(v.y)), fmaxf(fabsf(v.z), fabsf(v.w)));
}
__device__ __forceinline__ void gload16(const void* g, void* l) {
  __builtin_amdgcn_global_load_lds(
      (const __attribute__((address_space(1))) unsigned*)g,
      (__attribute__((address_space(3))) unsigned*)l, 16, 0, 0);
}
__device__ __forceinline__ void atomic_absmax(unsigned* out, float m, int lane) {
  #pragma unroll
  for (int o = 32; o >= 1; o >>= 1) m = fmaxf(m, __shfl_xor(m, o));
  if (lane == 0) atomicMax(out, __float_as_uint(m));
}

#define SB_() __builtin_amdgcn_sched_barrier(0)
#define PBAR() do { SB_(); __builtin_amdgcn_s_barrier(); SB_(); } while (0)
#define VM6() do { SB_(); asm volatile("s_waitcnt vmcnt(6)" ::: "memory"); } while (0)
#define VM0() do { SB_(); asm volatile("s_waitcnt vmcnt(0)" ::: "memory"); } while (0)

// work-proportional block partition for the 5 input tensors (2:4:1:1:4 /12)
__device__ __forceinline__ void tensor_pick(int blk, int& r, int& b0, int& nb) {
  if (blk < 342)       { r = 0; b0 = 0;    nb = 342; }
  else if (blk < 1024) { r = 1; b0 = 342;  nb = 682; }
  else if (blk < 1195) { r = 2; b0 = 1024; nb = 171; }
  else if (blk < 1366) { r = 3; b0 = 1195; nb = 171; }
  else                 { r = 4; b0 = 1366; nb = 682; }
}

// ---------------- fused absmax over the 5 input tensors ---------------------
__global__ void absmax5_k(const float4* __restrict__ p0, const float4* __restrict__ p1,
                          const float4* __restrict__ p2, const float4* __restrict__ p3,
                          const float4* __restrict__ p4, unsigned* __restrict__ sc) {
  int r, b0, nb;
  tensor_pick(blockIdx.x, r, b0, nb);
  const float4* x; int n4;
  if (r == 0)      { x = p0; n4 = B_ * S_ * HID / 4; }
  else if (r == 1) { x = p1; n4 = HID * HID / 4; }
  else if (r == 2) { x = p2; n4 = NKV * HD * HID / 4; }
  else if (r == 3) { x = p3; n4 = NKV * HD * HID / 4; }
  else             { x = p4; n4 = HID * HID / 4; }
  const int ng = n4 >> 2;
  const int stride = nb * 256;
  float m0 = 0.f, m1 = 0.f, m2 = 0.f, m3 = 0.f;
  for (int g = (blockIdx.x - b0) * 256 + threadIdx.x; g < ng; g += stride) {
    const float4* p = x + g * 4;
    float4 v0 = p[0], v1 = p[1], v2 = p[2], v3 = p[3];
    m0 = fmaxf(m0, max4(v0)); m1 = fmaxf(m1, max4(v1));
    m2 = fmaxf(m2, max4(v2)); m3 = fmaxf(m3, max4(v3));
  }
  float m = fmaxf(fmaxf(m0, m1), fmaxf(m2, m3));
  atomic_absmax(sc + r, m, threadIdx.x & 63);
}

// ---------------- fused quantize -> s8 --------------------------------------
__global__ void quant5_k(const float4* __restrict__ p0, const float4* __restrict__ p1,
                         const float4* __restrict__ p2, const float4* __restrict__ p3,
                         const float4* __restrict__ p4,
                         unsigned* __restrict__ y0, unsigned* __restrict__ y1,
                         unsigned* __restrict__ y2, unsigned* __restrict__ y3,
                         unsigned* __restrict__ y4, const unsigned* __restrict__ sc) {
  int r, b0, nb;
  tensor_pick(blockIdx.x, r, b0, nb);
  const float4* x; unsigned* y; int n4;
  if (r == 0)      { x = p0; y = y0; n4 = B_ * S_ * HID / 4; }
  else if (r == 1) { x = p1; y = y1; n4 = HID * HID / 4; }
  else if (r == 2) { x = p2; y = y2; n4 = NKV * HD * HID / 4; }
  else if (r == 3) { x = p3; y = y3; n4 = NKV * HD * HID / 4; }
  else             { x = p4; y = y4; n4 = HID * HID / 4; }
  float s = get_scale(sc, r);
  const int ng = n4 >> 2;
  const int stride = nb * 256;
  for (int g = (blockIdx.x - b0) * 256 + threadIdx.x; g < ng; g += stride) {
    const float4* p = x + g * 4;
    float4 v0 = p[0], v1 = p[1], v2 = p[2], v3 = p[3];
    uint4v o;
    o[0] = pack4(v0, s); o[1] = pack4(v1, s);
    o[2] = pack4(v2, s); o[3] = pack4(v3, s);
    *(uint4v*)(y + g * 4) = o;
  }
}

// ---------------- generic quantize (attn output) -> s8 ----------------------
__global__ void quant_k(const float4* __restrict__ x, unsigned* __restrict__ y, int n4,
                        const unsigned* __restrict__ sc, int slot) {
  float s = get_scale(sc, slot);
  const int ng = n4 >> 2;
  int stride = gridDim.x * blockDim.x;
  for (int g = blockIdx.x * blockDim.x + threadIdx.x; g < ng; g += stride) {
    const float4* p = x + g * 4;
    float4 v0 = p[0], v1 = p[1], v2 = p[2], v3 = p[3];
    uint4v o;
    o[0] = pack4(v0, s); o[1] = pack4(v1, s);
    o[2] = pack4(v2, s); o[3] = pack4(v3, s);
    *(uint4v*)(y + g * 4) = o;
  }
}

// ============ 256x256 8-phase int8 GEMM (verified core) ======================
// doRope: epilogue stages each 128x128 fp32 quadrant in LDS, applies RoPE
// (partner d^64 is in-tile since the tile holds whole heads), tracks roped
// absmax.  Math identical to the old rope2_k (same table, same fp32 ops).
__device__ __forceinline__ void rdA(const s8* slot, int wm, int lr, int lg,
                                    i32x4 af[4][2]) {
  #pragma unroll
  for (int mi = 0; mi < 4; ++mi) {
    int row = wm * 64 + mi * 16 + lr;
    const char* base = (const char*)slot + row * 128;
    int sw = (row & 7) << 4;
    #pragma unroll
    for (int ks = 0; ks < 2; ++ks)
      af[mi][ks] = *(const i32x4*)(base + ((ks * 64 + lg * 16) ^ sw));
  }
}
__device__ __forceinline__ void rdB(const s8* slot, int wn, int lr, int lg,
                                    i32x4 bf[2][2]) {
  #pragma unroll
  for (int ni = 0; ni < 2; ++ni) {
    int row = wn * 32 + ni * 16 + lr;
    const char* base = (const char*)slot + row * 128;
    int sw = (row & 7) << 4;
    #pragma unroll
    for (int ks = 0; ks < 2; ++ks)
      bf[ni][ks] = *(const i32x4*)(base + ((ks * 64 + lg * 16) ^ sw));
  }
}
template <int PM, int PN>
__device__ __forceinline__ void mfma_phase(i32x4 (&acc)[2][2][4][2],
                                           const i32x4 (&af)[4][2],
                                           const i32x4 (&bf)[2][2]) {
  __builtin_amdgcn_s_setprio(1);
  #pragma unroll
  for (int mi = 0; mi < 4; ++mi)
    #pragma unroll
    for (int ni = 0; ni < 2; ++ni)
      #pragma unroll
      for (int ks = 0; ks < 2; ++ks)
        acc[PM][PN][mi][ni] = mfma_i8(af[mi][ks], bf[ni][ks], acc[PM][PN][mi][ni]);
  __builtin_amdgcn_s_setprio(0);
}

__device__ void gemm256(const s8* __restrict__ A, const s8* __restrict__ Bm,
                        float* __restrict__ C, int Ncols, int m0, int n0,
                        int k0, int nkt, float scale, unsigned* omax,
                        const float2* __restrict__ tab, int doRope, s8* S) {
  const int tid = threadIdx.x;
  const int wave = tid >> 6, lane = tid & 63;
  const int lr = lane & 15, lg = lane >> 4;
  const int wm = wave >> 2, wn = wave & 3;
  s8* SA00 = S;          s8* SA01 = S + 16384;
  s8* SB00 = S + 32768;  s8* SB01 = S + 49152;
  s8* SA10 = S + 65536;  s8* SA11 = S + 81920;
  s8* SB10 = S + 98304;  s8* SB11 = S + 114688;
  const int r0 = tid >> 3;
  const int ce = ((tid & 7) * 16) ^ ((r0 & 7) << 4);
  const s8* pa0 = A + (size_t)(m0 + r0) * HID + k0 + ce;
  const s8* pa1 = pa0 + (size_t)128 * HID;
  const s8* pb0 = Bm + (size_t)(n0 + r0) * HID + k0 + ce;
  const s8* pb1 = pb0 + (size_t)128 * HID;
  const int wdst = wave * 1024;
  i32x4 acc[2][2][4][2] = {};
  i32x4 af[4][2], bf[2][2];

  auto STG = [&](const s8* p, s8* slot, int tcol) {
    const s8* g = p + tcol * 128;
    gload16(g, slot + wdst);
    gload16(g + (size_t)64 * HID, slot + 8192 + wdst);
  };

  STG(pa0, SA00, 0); STG(pb0, SB00, 0); STG(pa1, SA01, 0); STG(pb1, SB01, 0);
  STG(pa0, SA10, 1); STG(pb1, SB11, 1); STG(pa1, SA11, 1);
  VM6(); PBAR();

  #pragma unroll 1
  for (int t = 0; t < nkt; t += 2) {
    const bool g2 = t + 2 < nkt, g3 = t + 3 < nkt;
    rdA(SA00, wm, lr, lg, af); rdB(SB00, wn, lr, lg, bf);
    STG(pb0, SB10, t + 1);
    PBAR(); mfma_phase<0, 0>(acc, af, bf); PBAR();
    rdB(SB01, wn, lr, lg, bf);
    if (g2) STG(pa0, SA00, t + 2);
    PBAR(); mfma_phase<0, 1>(acc, af, bf); PBAR();
    rdA(SA01, wm, lr, lg, af);
    if (g2) STG(pb1, SB01, t + 2);
    PBAR(); mfma_phase<1, 1>(acc, af, bf); PBAR();
    rdB(SB00, wn, lr, lg, bf);
    if (g2) STG(pa1, SA01, t + 2);
    PBAR(); mfma_phase<1, 0>(acc, af, bf);
    if (g2) { VM6(); } else { VM0(); }
    PBAR();
    rdA(SA10, wm, lr, lg, af); rdB(SB10, wn, lr, lg, bf);
    if (g2) STG(pb0, SB00, t + 2);
    PBAR(); mfma_phase<0, 0>(acc, af, bf); PBAR();
    rdB(SB11, wn, lr, lg, bf);
    if (g3) STG(pa0, SA10, t + 3);
    PBAR(); mfma_phase<0, 1>(acc, af, bf); PBAR();
    rdA(SA11, wm, lr, lg, af);
    if (g3) STG(pb1, SB11, t + 3);
    PBAR(); mfma_phase<1, 1>(acc, af, bf); PBAR();
    rdB(SB10, wn, lr, lg, bf);
    if (g3) STG(pa1, SA11, t + 3);
    PBAR(); mfma_phase<1, 0>(acc, af, bf); VM6(); PBAR();
  }

  float gm = 0.f;
  if (!doRope) {
    #pragma unroll
    for (int mh = 0; mh < 2; ++mh)
      #pragma unroll
      for (int nh = 0; nh < 2; ++nh)
        #pragma unroll
        for (int mi = 0; mi < 4; ++mi)
          #pragma unroll
          for (int ni = 0; ni < 2; ++ni) {
            size_t rbase = (size_t)(m0 + mh * 128 + wm * 64 + mi * 16 + lg * 4);
            int cb = n0 + nh * 128 + wn * 32 + ni * 16 + lr;
            #pragma unroll
            for (int r = 0; r < 4; ++r) {
              float v = (float)acc[mh][nh][mi][ni][r] * scale;
              gm = fmaxf(gm, fabsf(v));
              C[(rbase + r) * (size_t)Ncols + cb] = v;
            }
          }
  } else {
    // RoPE epilogue: 4 quadrants of 128x128 fp32 via LDS partner exchange.
    __syncthreads();  // main-loop LDS dead (all stages drained by VM0)
    float* Lf = (float*)S;  // 64KB
    #pragma unroll
    for (int mh = 0; mh < 2; ++mh)
      #pragma unroll
      for (int nh = 0; nh < 2; ++nh) {
        #pragma unroll
        for (int mi = 0; mi < 4; ++mi)
          #pragma unroll
          for (int ni = 0; ni < 2; ++ni)
            #pragma unroll
            for (int r = 0; r < 4; ++r)
              Lf[(wm * 64 + mi * 16 + lg * 4 + r) * 128 + wn * 32 + ni * 16 + lr] =
                  (float)acc[mh][nh][mi][ni][r] * scale;
        __syncthreads();
        #pragma unroll
        for (int mi = 0; mi < 4; ++mi)
          #pragma unroll
          for (int ni = 0; ni < 2; ++ni)
            #pragma unroll
            for (int r = 0; r < 4; ++r) {
              int rloc = wm * 64 + mi * 16 + lg * 4 + r;
              int cloc = wn * 32 + ni * 16 + lr;
              float v = Lf[rloc * 128 + cloc];
              float w = Lf[rloc * 128 + (cloc ^ 64)];
              int grow = m0 + mh * 128 + rloc;
              float2 cs = tab[((grow & (S_ - 1)) << 6) + (cloc & 63)];
              float o = (cloc < 64) ? v * cs.x - w * cs.y : v * cs.x + w * cs.y;
              gm = fmaxf(gm, fabsf(o));
              C[(size_t)grow * Ncols + (n0 + nh * 128 + cloc)] = o;
            }
        __syncthreads();
      }
  }
  if (omax) atomic_absmax(omax, gm, lane);
}

// fused Q/K/V projection (+RoPE on Q/K): 192 blocks, XCD-swizzled
__global__ __launch_bounds__(512, 1) void gemm_qkv8(
    const s8* __restrict__ Xq, const s8* __restrict__ Wqb,
    const s8* __restrict__ Wkb, const s8* __restrict__ Wvb,
    float* __restrict__ qf, float* __restrict__ kf, float* __restrict__ vf,
    const unsigned* __restrict__ sc, unsigned* __restrict__ scq,
    const float2* __restrict__ tab) {
  extern __shared__ __align__(16) s8 S[];
  int raw = blockIdx.x;
  int wg = (raw & 7) * 24 + (raw >> 3);
  int bx = wg & 7, by = wg >> 3;
  const s8* Bm; float* C; int Ncols, n0, sslot, doRope; unsigned* om;
  if (by < 16)      { Bm = Wqb; C = qf; Ncols = HID;      n0 = by * 256;        sslot = 1; doRope = 1; om = scq + 5; }
  else if (by < 20) { Bm = Wkb; C = kf; Ncols = NKV * HD; n0 = (by - 16) * 256; sslot = 2; doRope = 1; om = scq + 6; }
  else              { Bm = Wvb; C = vf; Ncols = NKV * HD; n0 = (by - 20) * 256; sslot = 3; doRope = 0; om = scq + 7; }
  float scale = get_scale(sc, 0) * get_scale(sc, sslot);
  gemm256(Xq, Bm, C, Ncols, bx * 256, n0, 0, 32, scale, om, tab, doRope, S);
}

// O projection: direct (no split-K), 128 blocks, full K
__global__ __launch_bounds__(512, 1) void gemm_o8(
    const s8* __restrict__ A, const s8* __restrict__ Bm,
    float* __restrict__ Cout, const unsigned* __restrict__ sc) {
  extern __shared__ __align__(16) s8 S[];
  int raw = blockIdx.x;
  int wg = (raw & 7) * 16 + (raw >> 3);   // 128 = 8 XCD x 16, bijective
  int bx = wg >> 4, by = wg & 15;         // per-XCD: one A-panel x all Wo panels
  float scale = get_scale(sc, 8) * get_scale(sc, 4);
  gemm256(A, Bm, Cout, HID, bx * 256, by * 256, 0, 32, scale, nullptr,
          nullptr, 0, S);
}

// ---------------- RoPE cos/sin table (pos x 64) -----------------------------
__global__ void rope_tab_k(float2* __restrict__ tab) {
  int i = blockIdx.x * 256 + threadIdx.x;
  int pos = i >> 6, d = i & 63;
  float inv = exp2f((float)d * (-13.287712379549449f / 64.0f));
  float ang = (float)pos * inv;
  tab[i] = make_float2(cosf(ang), sinf(ang));
}

// ---------------- quantize q & k fused -> s8 --------------------------------
__global__ void quantqk_k(const float4* __restrict__ qf, const float4* __restrict__ kf,
                          unsigned* __restrict__ qq, unsigned* __restrict__ kq,
                          const unsigned* __restrict__ sc) {
  int reg = blockIdx.y;
  const float4* x = reg ? kf : qf;
  unsigned* y = reg ? kq : qq;
  int n4 = reg ? (B_ * S_ * NKV * HD / 4) : (B_ * S_ * HID / 4);
  float s = get_scale(sc, reg ? 6 : 5);
  const int ng = n4 >> 2;
  int stride = gridDim.x * blockDim.x;
  for (int g = blockIdx.x * blockDim.x + threadIdx.x; g < ng; g += stride) {
    const float4* p = x + g * 4;
    float4 v0 = p[0], v1 = p[1], v2 = p[2], v3 = p[3];
    uint4v o;
    o[0] = pack4(v0, s); o[1] = pack4(v1, s);
    o[2] = pack4(v2, s); o[3] = pack4(v3, s);
    *(uint4v*)(y + g * 4) = o;
  }
}

// ---------------- V: quantize + transpose to d-pair-packed s8 layout --------
__global__ __launch_bounds__(256) void vquant_t_k(const float* __restrict__ vf,
                                                  s8* __restrict__ vt,
                                                  const unsigned* __restrict__ sc) {
  __shared__ __align__(16) s8 Ls[64][132];
  float s = get_scale(sc, 7);
  int st = blockIdx.x & 15, kvh = (blockIdx.x >> 4) & 7, b = blockIdx.x >> 7;
  int s0 = st * 64;
  #pragma unroll
  for (int i = 0; i < 8; ++i) {
    int o = i * 256 + threadIdx.x;
    int sr = o >> 5, c4 = o & 31;
    float4 v = *(const float4*)(vf + ((size_t)(b * S_ + s0 + sr)) * (NKV * HD) +
                                kvh * HD + c4 * 4);
    *(unsigned*)(&Ls[sr][c4 * 4]) =
        (q127(v.x, s) & 255) | ((q127(v.y, s) & 255) << 8) |
        ((q127(v.z, s) & 255) << 16) | ((q127(v.w, s) & 255) << 24);
  }
  __syncthreads();
  s8* base = vt + (size_t)(b * NKV + kvh) * 131072 + st * 128;
  #pragma unroll
  for (int i = 0; i < 8; ++i) {
    int o = i * 256 + threadIdx.x;
    int j = o >> 5, half = (o >> 4) & 1, w = o & 15;
    int d = 2 * j + half;
    unsigned pk = (unsigned)(unsigned char)Ls[4 * w + 0][d] |
                  ((unsigned)(unsigned char)Ls[4 * w + 1][d] << 8) |
                  ((unsigned)(unsigned char)Ls[4 * w + 2][d] << 16) |
                  ((unsigned)(unsigned char)Ls[4 * w + 3][d] << 24);
    *(unsigned*)(base + (size_t)j * 2048 + half * 64 + ((w * 4) ^ ((j & 3) << 4))) = pk;
  }
}

// ---------------- two-pass quantized causal GQA attention (all-i8 MFMA) -----
__global__ __launch_bounds__(512) void attn_k(
    const s8* __restrict__ Q, const s8* __restrict__ Kq, const s8* __restrict__ Vt,
    float* __restrict__ O, const unsigned* __restrict__ sc, unsigned* __restrict__ omax) {
  __shared__ __align__(16) s8 Ks[2][64 * 128];
  __shared__ __align__(16) s8 Vs[2][64 * 128];
  __shared__ __align__(16) s8 Ps[128 * 64];
  const int tid = threadIdx.x;
  const int wave = tid >> 6, lane = tid & 63;
  const int lr = lane & 15, lg = lane >> 4;
  const int raw = blockIdx.x;
  const int xcd = raw & 7, j = raw >> 3;
  const int grp = xcd + 8 * (j >> 4);
  const int within = j & 15;
  const int b = grp >> 3, kvh = grp & 7;
  const int h = kvh * 4 + (within >> 2);
  const int qp = within & 3;
  const float sq = get_scale(sc, 5), sk = get_scale(sc, 6), sv = get_scale(sc, 7);
  const float c2 = sq * sk * 0.08838834764831845f * LOG2E;
  const float M0 = 32.0f;
  const int k_row = tid >> 3;
  const int k_cb = ((tid & 7) * 16) ^ ((k_row & 7) << 4);
  const s8* vbase = Vt + (size_t)(b * NKV + kvh) * 131072 +
                    (size_t)(tid >> 3) * 2048 + (tid & 7) * 16;
  float gmax = 0.f;

  auto stageK = [&](int buf, int kt) {
    gload16(Kq + (size_t)(b * S_ + kt * 64 + k_row) * (NKV * HD) + kvh * HD + k_cb,
            Ks[buf] + wave * 1024);
  };
  auto stageV = [&](int buf, int kt) {
    gload16(vbase + kt * 128, Vs[buf] + wave * 1024);
  };

  for (int pi = 0; pi < 2; ++pi) {
    const int qt = pi ? 7 - qp : qp;
    const int q0 = qt * 128;
    const int nkt = 2 * (qt + 1);
    const int qwmin = q0 + wave * 16;
    i32x4 aq[2];
    {
      const s8* qp_ = Q + (size_t)(b * S_ + q0 + wave * 16 + lr) * HID + h * HD + lg * 16;
      aq[0] = *(const i32x4*)(qp_);
      aq[1] = *(const i32x4*)(qp_ + 64);
    }
    float ll[4] = {0.f, 0.f, 0.f, 0.f};

    stageK(0, 0);
    __syncthreads();
    for (int kt = 0; kt < nkt; ++kt) {
      const int p = kt & 1;
      if (kt < nkt - 1) stageK(p ^ 1, kt + 1);
      i32x4 sacc[4] = {};
      __builtin_amdgcn_s_setprio(1);
      #pragma unroll
      for (int ks = 0; ks < 2; ++ks)
        #pragma unroll
        for (int n = 0; n < 4; ++n) {
          int row = n * 16 + lr;
          i32x4 bk = *(const i32x4*)((const char*)Ks[p] + row * 128 +
                                     ((ks * 64 + lg * 16) ^ ((row & 7) << 4)));
          sacc[n] = mfma_i8(aq[ks], bk, sacc[n]);
        }
      __builtin_amdgcn_s_setprio(0);
      if (kt * 64 + 63 <= qwmin) {
        #pragma unroll
        for (int r = 0; r < 4; ++r)
          #pragma unroll
          for (int n = 0; n < 4; ++n)
            ll[r] += exp2f(fmaf((float)sacc[n][r], c2, -M0));
      } else {
        #pragma unroll
        for (int r = 0; r < 4; ++r) {
          int qg = qwmin + lg * 4 + r;
          #pragma unroll
          for (int n = 0; n < 4; ++n) {
            int kg = kt * 64 + n * 16 + lr;
            float e = exp2f(fmaf((float)sacc[n][r], c2, -M0));
            ll[r] += (kg <= qg) ? e : 0.f;
          }
        }
      }
      __syncthreads();
    }
    float bias[4];
    #pragma unroll
    for (int r = 0; r < 4; ++r) {
      float l = ll[r];
      #pragma unroll
      for (int o = 8; o >= 1; o >>= 1) l += __shfl_xor(l, o);
      bias[r] = 6.9886846867721655f - __log2f(l) - M0;
    }

    i32x4 oacc[8] = {};
    stageK(0, 0); stageV(0, 0);
    __syncthreads();
    for (int kt = 0; kt < nkt; ++kt) {
      const int p = kt & 1;
      if (kt < nkt - 1) { stageK(p ^ 1, kt + 1); stageV(p ^ 1, kt + 1); }
      i32x4 sacc[4] = {};
      __builtin_amdgcn_s_setprio(1);
      #pragma unroll
      for (int ks = 0; ks < 2; ++ks)
        #pragma unroll
        for (int n = 0; n < 4; ++n) {
          int row = n * 16 + lr;
          i32x4 bk = *(const i32x4*)((const char*)Ks[p] + row * 128 +
                                     ((ks * 64 + lg * 16) ^ ((row & 7) << 4)));
          sacc[n] = mfma_i8(aq[ks], bk, sacc[n]);
        }
      __builtin_amdgcn_s_setprio(0);
      if (kt * 64 + 63 <= qwmin) {
        #pragma unroll
        for (int r = 0; r < 4; ++r) {
          int prow = wave * 16 + lg * 4 + r;
          s8* pr = Ps + prow * 64;
          #pragma unroll
          for (int n = 0; n < 4; ++n) {
            float p127 = rintf(exp2f(fmaf((float)sacc[n][r], c2, bias[r])));
            pr[((n * 16) ^ (lg << 4)) + lr] = (s8)(int)p127;
          }
        }
      } else {
        #pragma unroll
        for (int r = 0; r < 4; ++r) {
          int prow = wave * 16 + lg * 4 + r;
          int qg = qwmin + lg * 4 + r;
          s8* pr = Ps + prow * 64;
          #pragma unroll
          for (int n = 0; n < 4; ++n) {
            int kg = kt * 64 + n * 16 + lr;
            float a = fmaf((float)sacc[n][r], c2, bias[r]);
            float p127 = (kg <= qg) ? rintf(exp2f(a)) : 0.f;
            pr[((n * 16) ^ (lg << 4)) + lr] = (s8)(int)p127;
          }
        }
      }
      __builtin_amdgcn_s_setprio(1);
      {
        i32x4 ap = *(const i32x4*)(Ps + (wave * 16 + lr) * 64 +
                                   ((lg * 16) ^ (((lr >> 2) & 3) << 4)));
        #pragma unroll
        for (int n = 0; n < 8; ++n) {
          int jd = n * 8 + (lr >> 1);
          i32x4 bv = *(const i32x4*)((const char*)Vs[p] + jd * 128 + (lr & 1) * 64 +
                                     ((lg * 16) ^ ((jd & 3) << 4)));
          oacc[n] = mfma_i8(ap, bv, oacc[n]);
        }
      }
      __builtin_amdgcn_s_setprio(0);
      __syncthreads();
    }
    const float pvs = sv * (1.0f / 127.0f);
    #pragma unroll
    for (int n = 0; n < 8; ++n)
      #pragma unroll
      for (int r = 0; r < 4; ++r) {
        float v = (float)oacc[n][r] * pvs;
        gmax = fmaxf(gmax, fabsf(v));
        O[(size_t)(b * S_ + q0 + wave * 16 + lg * 4 + r) * HID + h * HD + n * 16 + lr] = v;
      }
  }
  atomic_absmax(omax, gmax, lane);
}

// ---------------------------------------------------------------------------
extern "C" void kernel_launch(void* const* d_in, const int* in_sizes, int n_in,
                              void* d_out, int out_size, void* d_ws, size_t ws_size,
                              hipStream_t stream) {
  const float* hs = (const float*)d_in[0];
  const float* Wq = (const float*)d_in[3];
  const float* Wk = (const float*)d_in[4];
  const float* Wv = (const float*)d_in[5];
  const float* Wo = (const float*)d_in[6];
  float* out = (float*)d_out;
  char* ws = (char*)d_ws;

  unsigned* sc = (unsigned*)ws;  // 0=x 1=Wq 2=Wk 3=Wv 4=Wo 5=q 6=k 7=v 8=attn_out
  size_t off = 256;
  s8* Xq = (s8*)(ws + off); off += (size_t)B_ * S_ * HID;
  size_t wqb_off = off;
  s8* Wqb = (s8*)(ws + off); off += (size_t)HID * HID;
  s8* Wkb = (s8*)(ws + off); off += (size_t)NKV * HD * HID;
  s8* Wvb = (s8*)(ws + off); off += (size_t)NKV * HD * HID;
  s8* Wob = (s8*)(ws + off); off += (size_t)HID * HID;
  size_t qf_off = off;
  float* qf = (float*)(ws + off); off += (size_t)B_ * S_ * HID * 4;
  float* kf = (float*)(ws + off); off += (size_t)B_ * S_ * NKV * HD * 4;
  float* vf = (float*)(ws + off); off += (size_t)B_ * S_ * NKV * HD * 4;
  s8* qq = (s8*)(ws + off); off += (size_t)B_ * S_ * HID;
  s8* kq = (s8*)(ws + off); off += (size_t)B_ * S_ * NKV * HD;
  s8* vt = (s8*)(ws + off); off += (size_t)B_ * S_ * NKV * HD;
  float2* tab = (float2*)(ws + off); off += (size_t)S_ * 64 * 8;
  float* attnf = (float*)(ws + qf_off);  // alias qf (dead after quantqk)
  s8* attnq = (s8*)(ws + wqb_off);       // alias Wqb (dead after gemm_qkv8)

  hipFuncSetAttribute((const void*)gemm_qkv8,
                      hipFuncAttributeMaxDynamicSharedMemorySize, 131072);
  hipFuncSetAttribute((const void*)gemm_o8,
                      hipFuncAttributeMaxDynamicSharedMemorySize, 131072);

  hipMemsetAsync(sc, 0, 64, stream);

  dim3 blk(256);
  absmax5_k<<<2048, blk, 0, stream>>>(
      (const float4*)hs, (const float4*)Wq, (const float4*)Wk,
      (const float4*)Wv, (const float4*)Wo, sc);
  quant5_k<<<2048, blk, 0, stream>>>(
      (const float4*)hs, (const float4*)Wq, (const float4*)Wk,
      (const float4*)Wv, (const float4*)Wo,
      (unsigned*)Xq, (unsigned*)Wqb, (unsigned*)Wkb, (unsigned*)Wvb,
      (unsigned*)Wob, sc);
  rope_tab_k<<<256, blk, 0, stream>>>(tab);

  gemm_qkv8<<<192, 512, 131072, stream>>>(Xq, Wqb, Wkb, Wvb, qf, kf, vf,
                                          sc, sc, tab);

  quantqk_k<<<dim3(512, 2), blk, 0, stream>>>((const float4*)qf, (const float4*)kf,
                                              (unsigned*)qq, (unsigned*)kq, sc);
  vquant_t_k<<<256, blk, 0, stream>>>(vf, vt, sc);

  attn_k<<<256, 512, 0, stream>>>(qq, kq, vt, attnf, sc, sc + 8);

  quant_k<<<2048, blk, 0, stream>>>((const float4*)attnf, (unsigned*)attnq,
                                    B_ * S_ * HID / 4, sc, 8);
  gemm_o8<<<128, 512, 131072, stream>>>(attnq, Wob, out, sc);
}

// Round 16
// 447.150 us; speedup vs baseline: 1.0334x; 1.0334x over previous
//
#include <hip/hip_runtime.h>
#include <math.h>

#define B_ 2
#define S_ 1024
#define HID 4096
#define NH 32
#define NKV 8
#define HD 128
#define LOG2E 1.44269504088896340736f

typedef short s16x8 __attribute__((ext_vector_type(8)));
typedef float f32x4 __attribute__((ext_vector_type(4)));
typedef int i32x4 __attribute__((ext_vector_type(4)));
typedef unsigned short u16;
typedef unsigned uint4v __attribute__((ext_vector_type(4)));
typedef signed char s8;

__device__ __forceinline__ i32x4 mfma_i8(i32x4 a, i32x4 b, i32x4 c) {
  return __builtin_amdgcn_mfma_i32_16x16x64_i8(a, b, c, 0, 0, 0);
}
__device__ __forceinline__ float get_scale(const unsigned* sc, int slot) {
  return fmaxf(__uint_as_float(sc[slot]) / 127.0f, 1e-8f);
}
__device__ __forceinline__ int q127(float x, float s) {
  return (int)fminf(fmaxf(rintf(x / s), -127.f), 127.f);
}
__device__ __forceinline__ unsigned pack4(float4 v, float s) {
  return (q127(v.x, s) & 255) | ((q127(v.y, s) & 255) << 8) |
         ((q127(v.z, s) & 255) << 16) | ((q127(v.w, s) & 255) << 24);
}
__device__ __forceinline__ float max4(float4 v) {
  return fmaxf(fmaxf(fabsf(v.x), fabsf(v.y)), fmaxf(fabsf(v.z), fabsf(v.w)));
}
__device__ __forceinline__ void gload16(const void* g, void* l) {
  __builtin_amdgcn_global_load_lds(
      (const __attribute__((address_space(1))) unsigned*)g,
      (__attribute__((address_space(3))) unsigned*)l, 16, 0, 0);
}
__device__ __forceinline__ void atomic_absmax(unsigned* out, float m, int lane) {
  #pragma unroll
  for (int o = 32; o >= 1; o >>= 1) m = fmaxf(m, __shfl_xor(m, o));
  if (lane == 0) atomicMax(out, __float_as_uint(m));
}

#define SB_() __builtin_amdgcn_sched_barrier(0)
#define PBAR() do { SB_(); __builtin_amdgcn_s_barrier(); SB_(); } while (0)
#define VM6() do { SB_(); asm volatile("s_waitcnt vmcnt(6)" ::: "memory"); } while (0)
#define VM0() do { SB_(); asm volatile("s_waitcnt vmcnt(0)" ::: "memory"); } while (0)

// work-proportional block partition for the 5 input tensors (2:4:1:1:4 /12)
__device__ __forceinline__ void tensor_pick(int blk, int& r, int& b0, int& nb) {
  if (blk < 342)       { r = 0; b0 = 0;    nb = 342; }
  else if (blk < 1024) { r = 1; b0 = 342;  nb = 682; }
  else if (blk < 1195) { r = 2; b0 = 1024; nb = 171; }
  else if (blk < 1366) { r = 3; b0 = 1195; nb = 171; }
  else                 { r = 4; b0 = 1366; nb = 682; }
}

// ---------------- fused absmax: 64B/thread contiguous batches (MLP=4) -------
__global__ void absmax5_k(const float4* __restrict__ p0, const float4* __restrict__ p1,
                          const float4* __restrict__ p2, const float4* __restrict__ p3,
                          const float4* __restrict__ p4, unsigned* __restrict__ sc) {
  int r, b0, nb;
  tensor_pick(blockIdx.x, r, b0, nb);
  const float4* x; int n4;
  if (r == 0)      { x = p0; n4 = B_ * S_ * HID / 4; }
  else if (r == 1) { x = p1; n4 = HID * HID / 4; }
  else if (r == 2) { x = p2; n4 = NKV * HD * HID / 4; }
  else if (r == 3) { x = p3; n4 = NKV * HD * HID / 4; }
  else             { x = p4; n4 = HID * HID / 4; }
  const int ng = n4 >> 2;  // groups of 4 float4 (64B)
  const int stride = nb * 256;
  float m0 = 0.f, m1 = 0.f, m2 = 0.f, m3 = 0.f;
  for (int g = (blockIdx.x - b0) * 256 + threadIdx.x; g < ng; g += stride) {
    const float4* p = x + g * 4;
    float4 v0 = p[0], v1 = p[1], v2 = p[2], v3 = p[3];
    m0 = fmaxf(m0, max4(v0)); m1 = fmaxf(m1, max4(v1));
    m2 = fmaxf(m2, max4(v2)); m3 = fmaxf(m3, max4(v3));
  }
  float m = fmaxf(fmaxf(m0, m1), fmaxf(m2, m3));
  atomic_absmax(sc + r, m, threadIdx.x & 63);
}

// ---------------- fused quantize -> s8, 64B in / 16B out per iter -----------
__global__ void quant5_k(const float4* __restrict__ p0, const float4* __restrict__ p1,
                         const float4* __restrict__ p2, const float4* __restrict__ p3,
                         const float4* __restrict__ p4,
                         unsigned* __restrict__ y0, unsigned* __restrict__ y1,
                         unsigned* __restrict__ y2, unsigned* __restrict__ y3,
                         unsigned* __restrict__ y4, const unsigned* __restrict__ sc) {
  int r, b0, nb;
  tensor_pick(blockIdx.x, r, b0, nb);
  const float4* x; unsigned* y; int n4;
  if (r == 0)      { x = p0; y = y0; n4 = B_ * S_ * HID / 4; }
  else if (r == 1) { x = p1; y = y1; n4 = HID * HID / 4; }
  else if (r == 2) { x = p2; y = y2; n4 = NKV * HD * HID / 4; }
  else if (r == 3) { x = p3; y = y3; n4 = NKV * HD * HID / 4; }
  else             { x = p4; y = y4; n4 = HID * HID / 4; }
  float s = get_scale(sc, r);
  const int ng = n4 >> 2;
  const int stride = nb * 256;
  for (int g = (blockIdx.x - b0) * 256 + threadIdx.x; g < ng; g += stride) {
    const float4* p = x + g * 4;
    float4 v0 = p[0], v1 = p[1], v2 = p[2], v3 = p[3];
    uint4v o;
    o[0] = pack4(v0, s); o[1] = pack4(v1, s);
    o[2] = pack4(v2, s); o[3] = pack4(v3, s);
    *(uint4v*)(y + g * 4) = o;
  }
}

// ---------------- generic quantize (attn output) -> s8 ----------------------
__global__ void quant_k(const float4* __restrict__ x, unsigned* __restrict__ y, int n4,
                        const unsigned* __restrict__ sc, int slot) {
  float s = get_scale(sc, slot);
  const int ng = n4 >> 2;
  int stride = gridDim.x * blockDim.x;
  for (int g = blockIdx.x * blockDim.x + threadIdx.x; g < ng; g += stride) {
    const float4* p = x + g * 4;
    float4 v0 = p[0], v1 = p[1], v2 = p[2], v3 = p[3];
    uint4v o;
    o[0] = pack4(v0, s); o[1] = pack4(v1, s);
    o[2] = pack4(v2, s); o[3] = pack4(v3, s);
    *(uint4v*)(y + g * 4) = o;
  }
}

// ---------------- split-K reduce: out = P0 + P1, 64B batches ----------------
__global__ void add_k(const float4* __restrict__ p0, const float4* __restrict__ p1,
                      float4* __restrict__ out, int n4) {
  const int ng = n4 >> 2;
  int stride = gridDim.x * blockDim.x;
  for (int g = blockIdx.x * blockDim.x + threadIdx.x; g < ng; g += stride) {
    const float4* a = p0 + g * 4;
    const float4* b = p1 + g * 4;
    float4 a0 = a[0], a1 = a[1], a2 = a[2], a3 = a[3];
    float4 b0 = b[0], b1 = b[1], b2 = b[2], b3 = b[3];
    float4* o = out + g * 4;
    o[0] = make_float4(a0.x + b0.x, a0.y + b0.y, a0.z + b0.z, a0.w + b0.w);
    o[1] = make_float4(a1.x + b1.x, a1.y + b1.y, a1.z + b1.z, a1.w + b1.w);
    o[2] = make_float4(a2.x + b2.x, a2.y + b2.y, a2.z + b2.z, a2.w + b2.w);
    o[3] = make_float4(a3.x + b3.x, a3.y + b3.y, a3.z + b3.z, a3.w + b3.w);
  }
}

// ============ 256x256 8-phase int8 GEMM (unchanged, verified) ================
__device__ __forceinline__ void rdA(const s8* slot, int wm, int lr, int lg,
                                    i32x4 af[4][2]) {
  #pragma unroll
  for (int mi = 0; mi < 4; ++mi) {
    int row = wm * 64 + mi * 16 + lr;
    const char* base = (const char*)slot + row * 128;
    int sw = (row & 7) << 4;
    #pragma unroll
    for (int ks = 0; ks < 2; ++ks)
      af[mi][ks] = *(const i32x4*)(base + ((ks * 64 + lg * 16) ^ sw));
  }
}
__device__ __forceinline__ void rdB(const s8* slot, int wn, int lr, int lg,
                                    i32x4 bf[2][2]) {
  #pragma unroll
  for (int ni = 0; ni < 2; ++ni) {
    int row = wn * 32 + ni * 16 + lr;
    const char* base = (const char*)slot + row * 128;
    int sw = (row & 7) << 4;
    #pragma unroll
    for (int ks = 0; ks < 2; ++ks)
      bf[ni][ks] = *(const i32x4*)(base + ((ks * 64 + lg * 16) ^ sw));
  }
}
template <int PM, int PN>
__device__ __forceinline__ void mfma_phase(i32x4 (&acc)[2][2][4][2],
                                           const i32x4 (&af)[4][2],
                                           const i32x4 (&bf)[2][2]) {
  __builtin_amdgcn_s_setprio(1);
  #pragma unroll
  for (int mi = 0; mi < 4; ++mi)
    #pragma unroll
    for (int ni = 0; ni < 2; ++ni)
      #pragma unroll
      for (int ks = 0; ks < 2; ++ks)
        acc[PM][PN][mi][ni] = mfma_i8(af[mi][ks], bf[ni][ks], acc[PM][PN][mi][ni]);
  __builtin_amdgcn_s_setprio(0);
}

__device__ void gemm256(const s8* __restrict__ A, const s8* __restrict__ Bm,
                        float* __restrict__ C, int Ncols, int m0, int n0,
                        int k0, int nkt, float scale, unsigned* omax, s8* S) {
  const int tid = threadIdx.x;
  const int wave = tid >> 6, lane = tid & 63;
  const int lr = lane & 15, lg = lane >> 4;
  const int wm = wave >> 2, wn = wave & 3;
  s8* SA00 = S;          s8* SA01 = S + 16384;
  s8* SB00 = S + 32768;  s8* SB01 = S + 49152;
  s8* SA10 = S + 65536;  s8* SA11 = S + 81920;
  s8* SB10 = S + 98304;  s8* SB11 = S + 114688;
  const int r0 = tid >> 3;
  const int ce = ((tid & 7) * 16) ^ ((r0 & 7) << 4);
  const s8* pa0 = A + (size_t)(m0 + r0) * HID + k0 + ce;
  const s8* pa1 = pa0 + (size_t)128 * HID;
  const s8* pb0 = Bm + (size_t)(n0 + r0) * HID + k0 + ce;
  const s8* pb1 = pb0 + (size_t)128 * HID;
  const int wdst = wave * 1024;
  i32x4 acc[2][2][4][2] = {};
  i32x4 af[4][2], bf[2][2];

  auto STG = [&](const s8* p, s8* slot, int tcol) {
    const s8* g = p + tcol * 128;
    gload16(g, slot + wdst);
    gload16(g + (size_t)64 * HID, slot + 8192 + wdst);
  };

  STG(pa0, SA00, 0); STG(pb0, SB00, 0); STG(pa1, SA01, 0); STG(pb1, SB01, 0);
  STG(pa0, SA10, 1); STG(pb1, SB11, 1); STG(pa1, SA11, 1);
  VM6(); PBAR();

  #pragma unroll 1
  for (int t = 0; t < nkt; t += 2) {
    const bool g2 = t + 2 < nkt, g3 = t + 3 < nkt;
    rdA(SA00, wm, lr, lg, af); rdB(SB00, wn, lr, lg, bf);
    STG(pb0, SB10, t + 1);
    PBAR(); mfma_phase<0, 0>(acc, af, bf); PBAR();
    rdB(SB01, wn, lr, lg, bf);
    if (g2) STG(pa0, SA00, t + 2);
    PBAR(); mfma_phase<0, 1>(acc, af, bf); PBAR();
    rdA(SA01, wm, lr, lg, af);
    if (g2) STG(pb1, SB01, t + 2);
    PBAR(); mfma_phase<1, 1>(acc, af, bf); PBAR();
    rdB(SB00, wn, lr, lg, bf);
    if (g2) STG(pa1, SA01, t + 2);
    PBAR(); mfma_phase<1, 0>(acc, af, bf);
    if (g2) { VM6(); } else { VM0(); }
    PBAR();
    rdA(SA10, wm, lr, lg, af); rdB(SB10, wn, lr, lg, bf);
    if (g2) STG(pb0, SB00, t + 2);
    PBAR(); mfma_phase<0, 0>(acc, af, bf); PBAR();
    rdB(SB11, wn, lr, lg, bf);
    if (g3) STG(pa0, SA10, t + 3);
    PBAR(); mfma_phase<0, 1>(acc, af, bf); PBAR();
    rdA(SA11, wm, lr, lg, af);
    if (g3) STG(pb1, SB11, t + 3);
    PBAR(); mfma_phase<1, 1>(acc, af, bf); PBAR();
    rdB(SB10, wn, lr, lg, bf);
    if (g3) STG(pa1, SA11, t + 3);
    PBAR(); mfma_phase<1, 0>(acc, af, bf); VM6(); PBAR();
  }

  float gm = 0.f;
  #pragma unroll
  for (int mh = 0; mh < 2; ++mh)
    #pragma unroll
    for (int nh = 0; nh < 2; ++nh)
      #pragma unroll
      for (int mi = 0; mi < 4; ++mi)
        #pragma unroll
        for (int ni = 0; ni < 2; ++ni) {
          size_t rbase = (size_t)(m0 + mh * 128 + wm * 64 + mi * 16 + lg * 4);
          int cb = n0 + nh * 128 + wn * 32 + ni * 16 + lr;
          #pragma unroll
          for (int r = 0; r < 4; ++r) {
            float v = (float)acc[mh][nh][mi][ni][r] * scale;
            gm = fmaxf(gm, fabsf(v));
            C[(rbase + r) * (size_t)Ncols + cb] = v;
          }
        }
  if (omax) atomic_absmax(omax, gm, lane);
}

__global__ __launch_bounds__(512, 1) void gemm_qkv8(
    const s8* __restrict__ Xq, const s8* __restrict__ Wqb,
    const s8* __restrict__ Wkb, const s8* __restrict__ Wvb,
    float* __restrict__ qf, float* __restrict__ kf, float* __restrict__ vf,
    const unsigned* __restrict__ sc, unsigned* __restrict__ vmax) {
  extern __shared__ __align__(16) s8 S[];
  int raw = blockIdx.x;
  int wg = (raw & 7) * 24 + (raw >> 3);
  int bx = wg & 7, by = wg >> 3;
  const s8* Bm; float* C; int Ncols, n0, sslot; unsigned* om = nullptr;
  if (by < 16)      { Bm = Wqb; C = qf; Ncols = HID;      n0 = by * 256;        sslot = 1; }
  else if (by < 20) { Bm = Wkb; C = kf; Ncols = NKV * HD; n0 = (by - 16) * 256; sslot = 2; }
  else              { Bm = Wvb; C = vf; Ncols = NKV * HD; n0 = (by - 20) * 256; sslot = 3; om = vmax; }
  float scale = get_scale(sc, 0) * get_scale(sc, sslot);
  gemm256(Xq, Bm, C, Ncols, bx * 256, n0, 0, 32, scale, om, S);
}

__global__ __launch_bounds__(512, 1) void gemm_o8(
    const s8* __restrict__ A, const s8* __restrict__ Bm,
    float* __restrict__ P0, float* __restrict__ P1,
    const unsigned* __restrict__ sc) {
  extern __shared__ __align__(16) s8 S[];
  int raw = blockIdx.x;
  int wg = (raw & 7) * 32 + (raw >> 3);
  int tile = wg >> 1, half = wg & 1;
  int by = tile & 15, bx = tile >> 4;
  float scale = get_scale(sc, 8) * get_scale(sc, 4);
  gemm256(A, Bm, half ? P1 : P0, HID, bx * 256, by * 256, half * 2048, 16,
          scale, nullptr, S);
}

// ---------------- RoPE cos/sin table (pos x 64) -----------------------------
__global__ void rope_tab_k(float2* __restrict__ tab) {
  int i = blockIdx.x * 256 + threadIdx.x;
  int pos = i >> 6, d = i & 63;
  float inv = exp2f((float)d * (-13.287712379549449f / 64.0f));
  float ang = (float)pos * inv;
  tab[i] = make_float2(cosf(ang), sinf(ang));
}

// ---------------- RoPE in-place + absmax, q & k fused, float4 ---------------
__global__ void rope2_k(float* __restrict__ qf, float* __restrict__ kf,
                        unsigned* __restrict__ sc, const float2* __restrict__ tab) {
  int reg = blockIdx.y;
  float* q = reg ? kf : qf;
  int nheads = reg ? NKV : NH;
  unsigned* om = sc + (reg ? 6 : 5);
  int total = B_ * S_ * nheads * 16;
  int stride = gridDim.x * blockDim.x;
  float m = 0.f;
  for (int i = blockIdx.x * blockDim.x + threadIdx.x; i < total; i += stride) {
    int g = i & 15;
    int h = (i >> 4) % nheads;
    int bs = i / (16 * nheads);
    int pos = bs & (S_ - 1);
    size_t base = ((size_t)bs * nheads + h) * HD + g * 4;
    float4 x1 = *(float4*)(q + base);
    float4 x2 = *(float4*)(q + base + 64);
    const float4* t = (const float4*)(tab + ((size_t)pos << 6) + g * 4);
    float4 t0 = t[0], t1 = t[1];
    float4 o1, o2;
    o1.x = x1.x * t0.x - x2.x * t0.y;  o2.x = x2.x * t0.x + x1.x * t0.y;
    o1.y = x1.y * t0.z - x2.y * t0.w;  o2.y = x2.y * t0.z + x1.y * t0.w;
    o1.z = x1.z * t1.x - x2.z * t1.y;  o2.z = x2.z * t1.x + x1.z * t1.y;
    o1.w = x1.w * t1.z - x2.w * t1.w;  o2.w = x2.w * t1.z + x1.w * t1.w;
    *(float4*)(q + base) = o1;
    *(float4*)(q + base + 64) = o2;
    m = fmaxf(m, fmaxf(max4(o1), max4(o2)));
  }
  atomic_absmax(om, m, threadIdx.x & 63);
}

// ---------------- quantize q & k fused -> s8 --------------------------------
__global__ void quantqk_k(const float4* __restrict__ qf, const float4* __restrict__ kf,
                          unsigned* __restrict__ qq, unsigned* __restrict__ kq,
                          const unsigned* __restrict__ sc) {
  int reg = blockIdx.y;
  const float4* x = reg ? kf : qf;
  unsigned* y = reg ? kq : qq;
  int n4 = reg ? (B_ * S_ * NKV * HD / 4) : (B_ * S_ * HID / 4);
  float s = get_scale(sc, reg ? 6 : 5);
  const int ng = n4 >> 2;
  int stride = gridDim.x * blockDim.x;
  for (int g = blockIdx.x * blockDim.x + threadIdx.x; g < ng; g += stride) {
    const float4* p = x + g * 4;
    float4 v0 = p[0], v1 = p[1], v2 = p[2], v3 = p[3];
    uint4v o;
    o[0] = pack4(v0, s); o[1] = pack4(v1, s);
    o[2] = pack4(v2, s); o[3] = pack4(v3, s);
    *(uint4v*)(y + g * 4) = o;
  }
}

// ---------------- V: quantize + transpose to d-pair-packed s8 layout --------
// Per (b,kvh): 64 rows j (=d>>1) x 2048B; row j, kv-tile kt occupies bytes
// kt*128 + (d&1)*64 + (kv_in ^ swz) with swz = ((j&3)<<4) baked in (so attn
// stages LINEARLY and reads with the same XOR; rule #21).
__global__ __launch_bounds__(256) void vquant_t_k(const float* __restrict__ vf,
                                                  s8* __restrict__ vt,
                                                  const unsigned* __restrict__ sc) {
  __shared__ __align__(16) s8 Ls[64][132];
  float s = get_scale(sc, 7);
  int st = blockIdx.x & 15, kvh = (blockIdx.x >> 4) & 7, b = blockIdx.x >> 7;
  int s0 = st * 64;
  #pragma unroll
  for (int i = 0; i < 8; ++i) {
    int o = i * 256 + threadIdx.x;
    int sr = o >> 5, c4 = o & 31;
    float4 v = *(const float4*)(vf + ((size_t)(b * S_ + s0 + sr)) * (NKV * HD) +
                                kvh * HD + c4 * 4);
    *(unsigned*)(&Ls[sr][c4 * 4]) =
        (q127(v.x, s) & 255) | ((q127(v.y, s) & 255) << 8) |
        ((q127(v.z, s) & 255) << 16) | ((q127(v.w, s) & 255) << 24);
  }
  __syncthreads();
  s8* base = vt + (size_t)(b * NKV + kvh) * 131072 + st * 128;
  #pragma unroll
  for (int i = 0; i < 8; ++i) {
    int o = i * 256 + threadIdx.x;
    int j = o >> 5, half = (o >> 4) & 1, w = o & 15;
    int d = 2 * j + half;
    unsigned pk = (unsigned)(unsigned char)Ls[4 * w + 0][d] |
                  ((unsigned)(unsigned char)Ls[4 * w + 1][d] << 8) |
                  ((unsigned)(unsigned char)Ls[4 * w + 2][d] << 16) |
                  ((unsigned)(unsigned char)Ls[4 * w + 3][d] << 24);
    *(unsigned*)(base + (size_t)j * 2048 + half * 64 + ((w * 4) ^ ((j & 3) << 4))) = pk;
  }
}

// ---------------- two-pass quantized causal GQA attention (all-i8 MFMA) -----
__global__ __launch_bounds__(512) void attn_k(
    const s8* __restrict__ Q, const s8* __restrict__ Kq, const s8* __restrict__ Vt,
    float* __restrict__ O, const unsigned* __restrict__ sc, unsigned* __restrict__ omax) {
  __shared__ __align__(16) s8 Ks[2][64 * 128];
  __shared__ __align__(16) s8 Vs[2][64 * 128];
  __shared__ __align__(16) s8 Ps[128 * 64];
  const int tid = threadIdx.x;
  const int wave = tid >> 6, lane = tid & 63;
  const int lr = lane & 15, lg = lane >> 4;
  const int raw = blockIdx.x;
  const int xcd = raw & 7, j = raw >> 3;
  const int grp = xcd + 8 * (j >> 4);
  const int within = j & 15;
  const int b = grp >> 3, kvh = grp & 7;
  const int h = kvh * 4 + (within >> 2);
  const int qp = within & 3;
  const float sq = get_scale(sc, 5), sk = get_scale(sc, 6), sv = get_scale(sc, 7);
  const float c2 = sq * sk * 0.08838834764831845f * LOG2E;
  const float M0 = 32.0f;
  const int k_row = tid >> 3;
  const int k_cb = ((tid & 7) * 16) ^ ((k_row & 7) << 4);
  const s8* vbase = Vt + (size_t)(b * NKV + kvh) * 131072 +
                    (size_t)(tid >> 3) * 2048 + (tid & 7) * 16;
  float gmax = 0.f;

  auto stageK = [&](int buf, int kt) {
    gload16(Kq + (size_t)(b * S_ + kt * 64 + k_row) * (NKV * HD) + kvh * HD + k_cb,
            Ks[buf] + wave * 1024);
  };
  auto stageV = [&](int buf, int kt) {
    gload16(vbase + kt * 128, Vs[buf] + wave * 1024);
  };

  for (int pi = 0; pi < 2; ++pi) {
    const int qt = pi ? 7 - qp : qp;
    const int q0 = qt * 128;
    const int nkt = 2 * (qt + 1);
    const int qwmin = q0 + wave * 16;
    i32x4 aq[2];
    {
      const s8* qp_ = Q + (size_t)(b * S_ + q0 + wave * 16 + lr) * HID + h * HD + lg * 16;
      aq[0] = *(const i32x4*)(qp_);
      aq[1] = *(const i32x4*)(qp_ + 64);
    }
    float ll[4] = {0.f, 0.f, 0.f, 0.f};

    // ---- pass 1: denominator only, fixed reference M0 ----
    stageK(0, 0);
    __syncthreads();
    for (int kt = 0; kt < nkt; ++kt) {
      const int p = kt & 1;
      if (kt < nkt - 1) stageK(p ^ 1, kt + 1);
      i32x4 sacc[4] = {};
      __builtin_amdgcn_s_setprio(1);
      #pragma unroll
      for (int ks = 0; ks < 2; ++ks)
        #pragma unroll
        for (int n = 0; n < 4; ++n) {
          int row = n * 16 + lr;
          i32x4 bk = *(const i32x4*)((const char*)Ks[p] + row * 128 +
                                     ((ks * 64 + lg * 16) ^ ((row & 7) << 4)));
          sacc[n] = mfma_i8(aq[ks], bk, sacc[n]);
        }
      __builtin_amdgcn_s_setprio(0);
      if (kt * 64 + 63 <= qwmin) {
        #pragma unroll
        for (int r = 0; r < 4; ++r)
          #pragma unroll
          for (int n = 0; n < 4; ++n)
            ll[r] += exp2f(fmaf((float)sacc[n][r], c2, -M0));
      } else {
        #pragma unroll
        for (int r = 0; r < 4; ++r) {
          int qg = qwmin + lg * 4 + r;
          #pragma unroll
          for (int n = 0; n < 4; ++n) {
            int kg = kt * 64 + n * 16 + lr;
            float e = exp2f(fmaf((float)sacc[n][r], c2, -M0));
            ll[r] += (kg <= qg) ? e : 0.f;
          }
        }
      }
      __syncthreads();
    }
    float bias[4];
    #pragma unroll
    for (int r = 0; r < 4; ++r) {
      float l = ll[r];
      #pragma unroll
      for (int o = 8; o >= 1; o >>= 1) l += __shfl_xor(l, o);
      bias[r] = 6.9886846867721655f - __log2f(l) - M0;
    }

    // ---- pass 2: recompute S, quantize P (s8), PV (i8) ----
    i32x4 oacc[8] = {};
    stageK(0, 0); stageV(0, 0);
    __syncthreads();
    for (int kt = 0; kt < nkt; ++kt) {
      const int p = kt & 1;
      if (kt < nkt - 1) { stageK(p ^ 1, kt + 1); stageV(p ^ 1, kt + 1); }
      i32x4 sacc[4] = {};
      __builtin_amdgcn_s_setprio(1);
      #pragma unroll
      for (int ks = 0; ks < 2; ++ks)
        #pragma unroll
        for (int n = 0; n < 4; ++n) {
          int row = n * 16 + lr;
          i32x4 bk = *(const i32x4*)((const char*)Ks[p] + row * 128 +
                                     ((ks * 64 + lg * 16) ^ ((row & 7) << 4)));
          sacc[n] = mfma_i8(aq[ks], bk, sacc[n]);
        }
      __builtin_amdgcn_s_setprio(0);
      if (kt * 64 + 63 <= qwmin) {
        #pragma unroll
        for (int r = 0; r < 4; ++r) {
          int prow = wave * 16 + lg * 4 + r;
          s8* pr = Ps + prow * 64;
          #pragma unroll
          for (int n = 0; n < 4; ++n) {
            float p127 = rintf(exp2f(fmaf((float)sacc[n][r], c2, bias[r])));
            pr[((n * 16) ^ (lg << 4)) + lr] = (s8)(int)p127;
          }
        }
      } else {
        #pragma unroll
        for (int r = 0; r < 4; ++r) {
          int prow = wave * 16 + lg * 4 + r;
          int qg = qwmin + lg * 4 + r;
          s8* pr = Ps + prow * 64;
          #pragma unroll
          for (int n = 0; n < 4; ++n) {
            int kg = kt * 64 + n * 16 + lr;
            float a = fmaf((float)sacc[n][r], c2, bias[r]);
            float p127 = (kg <= qg) ? rintf(exp2f(a)) : 0.f;
            pr[((n * 16) ^ (lg << 4)) + lr] = (s8)(int)p127;
          }
        }
      }
      // Ps wave-private: lgkmcnt orders ds_write -> ds_read, no barrier.
      __builtin_amdgcn_s_setprio(1);
      {
        i32x4 ap = *(const i32x4*)(Ps + (wave * 16 + lr) * 64 +
                                   ((lg * 16) ^ (((lr >> 2) & 3) << 4)));
        #pragma unroll
        for (int n = 0; n < 8; ++n) {
          int jd = n * 8 + (lr >> 1);
          i32x4 bv = *(const i32x4*)((const char*)Vs[p] + jd * 128 + (lr & 1) * 64 +
                                     ((lg * 16) ^ ((jd & 3) << 4)));
          oacc[n] = mfma_i8(ap, bv, oacc[n]);
        }
      }
      __builtin_amdgcn_s_setprio(0);
      __syncthreads();
    }
    const float pvs = sv * (1.0f / 127.0f);
    #pragma unroll
    for (int n = 0; n < 8; ++n)
      #pragma unroll
      for (int r = 0; r < 4; ++r) {
        float v = (float)oacc[n][r] * pvs;
        gmax = fmaxf(gmax, fabsf(v));
        O[(size_t)(b * S_ + q0 + wave * 16 + lg * 4 + r) * HID + h * HD + n * 16 + lr] = v;
      }
  }
  atomic_absmax(omax, gmax, lane);
}

// ---------------------------------------------------------------------------
extern "C" void kernel_launch(void* const* d_in, const int* in_sizes, int n_in,
                              void* d_out, int out_size, void* d_ws, size_t ws_size,
                              hipStream_t stream) {
  const float* hs = (const float*)d_in[0];
  const float* Wq = (const float*)d_in[3];
  const float* Wk = (const float*)d_in[4];
  const float* Wv = (const float*)d_in[5];
  const float* Wo = (const float*)d_in[6];
  float* out = (float*)d_out;
  char* ws = (char*)d_ws;

  unsigned* sc = (unsigned*)ws;  // 0=x 1=Wq 2=Wk 3=Wv 4=Wo 5=q 6=k 7=v 8=attn_out
  size_t off = 256;
  s8* Xq = (s8*)(ws + off); off += (size_t)B_ * S_ * HID;
  size_t wqb_off = off;
  s8* Wqb = (s8*)(ws + off); off += (size_t)HID * HID;
  s8* Wkb = (s8*)(ws + off); off += (size_t)NKV * HD * HID;
  s8* Wvb = (s8*)(ws + off); off += (size_t)NKV * HD * HID;
  s8* Wob = (s8*)(ws + off); off += (size_t)HID * HID;
  size_t qf_off = off;
  float* qf = (float*)(ws + off); off += (size_t)B_ * S_ * HID * 4;
  size_t kf_off = off;
  float* kf = (float*)(ws + off); off += (size_t)B_ * S_ * NKV * HD * 4;
  float* vf = (float*)(ws + off); off += (size_t)B_ * S_ * NKV * HD * 4;
  s8* qq = (s8*)(ws + off); off += (size_t)B_ * S_ * HID;
  s8* kq = (s8*)(ws + off); off += (size_t)B_ * S_ * NKV * HD;
  s8* vt = (s8*)(ws + off); off += (size_t)B_ * S_ * NKV * HD;
  float2* tab = (float2*)(ws + off); off += (size_t)S_ * 64 * 8;
  float* P1 = (float*)(ws + off); off += (size_t)B_ * S_ * HID * 4;
  float* attnf = (float*)(ws + qf_off);  // alias qf (dead after quantqk)
  s8* attnq = (s8*)(ws + wqb_off);       // alias Wqb (dead after gemm_qkv8)
  float* P0 = (float*)(ws + qf_off);     // alias qf (attnf consumed by quant_k)

  hipFuncSetAttribute((const void*)gemm_qkv8,
                      hipFuncAttributeMaxDynamicSharedMemorySize, 131072);
  hipFuncSetAttribute((const void*)gemm_o8,
                      hipFuncAttributeMaxDynamicSharedMemorySize, 131072);

  hipMemsetAsync(sc, 0, 64, stream);

  dim3 blk(256);
  absmax5_k<<<2048, blk, 0, stream>>>(
      (const float4*)hs, (const float4*)Wq, (const float4*)Wk,
      (const float4*)Wv, (const float4*)Wo, sc);
  quant5_k<<<2048, blk, 0, stream>>>(
      (const float4*)hs, (const float4*)Wq, (const float4*)Wk,
      (const float4*)Wv, (const float4*)Wo,
      (unsigned*)Xq, (unsigned*)Wqb, (unsigned*)Wkb, (unsigned*)Wvb,
      (unsigned*)Wob, sc);
  rope_tab_k<<<256, blk, 0, stream>>>(tab);

  gemm_qkv8<<<192, 512, 131072, stream>>>(Xq, Wqb, Wkb, Wvb, qf, kf, vf, sc, sc + 7);

  rope2_k<<<dim3(512, 2), blk, 0, stream>>>(qf, kf, sc, tab);
  quantqk_k<<<dim3(512, 2), blk, 0, stream>>>((const float4*)qf, (const float4*)kf,
                                              (unsigned*)qq, (unsigned*)kq, sc);
  vquant_t_k<<<256, blk, 0, stream>>>(vf, vt, sc);

  attn_k<<<256, 512, 0, stream>>>(qq, kq, vt, attnf, sc, sc + 8);

  quant_k<<<2048, blk, 0, stream>>>((const float4*)attnf, (unsigned*)attnq,
                                    B_ * S_ * HID / 4, sc, 8);
  gemm_o8<<<256, 512, 131072, stream>>>(attnq, Wob, P0, P1, sc);
  add_k<<<2048, blk, 0, stream>>>((const float4*)P0, (const float4*)P1,
                                  (float4*)out, B_ * S_ * HID / 4);
}